// Round 1
// baseline (440.002 us; speedup 1.0000x reference)
//
#include <hip/hip_runtime.h>

// RA_MLA_Attention — MI355X (gfx950) implementation.
// B=1, T=2048, E=2048, H=16, D=128, L=64, RA_WINDOW=64, RA_ALPHA=0.5
//
// Key algebra:
//   logits_recip[t,s] = rowsum_l(q_latent[t,h,:]) * rowsum_l(latent_k[s,:])  (rank-1!)
//   q_latent = hs @ Wql^T  with  Wql[(h,l),e] = sum_d q2l[h,d,l]*Wq[h*128+d,e]
// Flash attention per (head, 64-row Q tile), online softmax, bf16 MFMA 16x16x32.

#define T_ 2048
#define E_ 2048
#define H_ 16
#define D_ 128
#define L_ 64

typedef float  floatx4 __attribute__((ext_vector_type(4)));
typedef __bf16 bf16x8  __attribute__((ext_vector_type(8)));

__device__ __forceinline__ ushort f2b(float x){           // fp32 -> bf16 bits, RNE
  unsigned int u = __float_as_uint(x);
  u = (u + 0x7fffu + ((u >> 16) & 1u)) >> 16;
  return (ushort)u;
}

// ---------------- fp32 -> bf16 convert ----------------
__global__ __launch_bounds__(256)
void k_f2b(const float* __restrict__ in, ushort* __restrict__ out, int n){
  int i = (blockIdx.x*256 + threadIdx.x)*4;
  if (i < n){
    float4 v = *(const float4*)(in + i);
    ushort4 o; o.x=f2b(v.x); o.y=f2b(v.y); o.z=f2b(v.z); o.w=f2b(v.w);
    *(ushort4*)(out + i) = o;
  }
}

// ---------------- fold q_to_latent into Wq:  Wql[(h,l),e] ----------------
__global__ __launch_bounds__(128)
void k_prep_wql(const float* __restrict__ Wq, const float* __restrict__ q2l,
                ushort* __restrict__ Wql){
  const int h = blockIdx.z, l0 = blockIdx.y*8;
  const int e = blockIdx.x*128 + threadIdx.x;
  __shared__ float qs[128][8];                 // q2l[h, d, l0..l0+8)
  for (int c = threadIdx.x; c < 1024; c += 128)
    qs[c>>3][c&7] = q2l[(size_t)h*D_*L_ + (size_t)(c>>3)*L_ + l0 + (c&7)];
  __syncthreads();
  float acc[8] = {0,0,0,0,0,0,0,0};
  for (int d=0; d<128; ++d){
    float w = Wq[(size_t)(h*128+d)*E_ + e];    // coalesced
    #pragma unroll
    for (int i=0;i<8;++i) acc[i] += w*qs[d][i];
  }
  #pragma unroll
  for (int i=0;i<8;++i) Wql[(size_t)(h*64 + l0 + i)*E_ + e] = f2b(acc[i]);
}

// ---------------- bf16 MFMA GEMM:  C[M,N] = A[M,K] @ B[N,K]^T ----------------
// Verified gfx950 layouts: A/B frag m|n=lane&15,k=quad*8+j ; C/D row=quad*4+r,col=lane&15
template<int WGM,int WGN,int MT,int NT,bool OF32,bool OB16>
__global__ __launch_bounds__(WGM*WGN*64)
void gemm_bt(const ushort* __restrict__ A, const ushort* __restrict__ B,
             float* __restrict__ Cf, ushort* __restrict__ Cb,
             int M, int N, int K){
  constexpr int BM = WGM*MT*16, BN = WGN*NT*16, BK = 32;
  constexpr int NTHR = WGM*WGN*64;
  constexpr int LDT = BK + 8;                 // 40 bf16 = 80B rows: 16B-aligned, 2-way banks (free)
  __shared__ ushort As[BM*LDT];
  __shared__ ushort Bs[BN*LDT];
  const int tid = threadIdx.x, lane = tid & 63, wv = tid >> 6;
  const int wm = wv % WGM, wn = wv / WGM;
  const int l15 = lane & 15, quad = lane >> 4;
  const int m0 = blockIdx.y*BM, n0 = blockIdx.x*BN;
  floatx4 acc[MT][NT] = {};
  for (int k0 = 0; k0 < K; k0 += BK){
    #pragma unroll
    for (int c = tid; c < BM*BK/8; c += NTHR){
      int row = c >> 2, kc = (c & 3)*8;
      *(uint4*)(&As[row*LDT + kc]) = *(const uint4*)(A + (size_t)(m0+row)*K + k0 + kc);
    }
    #pragma unroll
    for (int c = tid; c < BN*BK/8; c += NTHR){
      int row = c >> 2, kc = (c & 3)*8;
      *(uint4*)(&Bs[row*LDT + kc]) = *(const uint4*)(B + (size_t)(n0+row)*K + k0 + kc);
    }
    __syncthreads();
    bf16x8 af[MT], bfr[NT];
    #pragma unroll
    for (int mi=0; mi<MT; ++mi)
      af[mi] = *(const bf16x8*)(&As[(wm*MT*16 + mi*16 + l15)*LDT + quad*8]);
    #pragma unroll
    for (int ni=0; ni<NT; ++ni)
      bfr[ni] = *(const bf16x8*)(&Bs[(wn*NT*16 + ni*16 + l15)*LDT + quad*8]);
    #pragma unroll
    for (int mi=0; mi<MT; ++mi)
      #pragma unroll
      for (int ni=0; ni<NT; ++ni)
        acc[mi][ni] = __builtin_amdgcn_mfma_f32_16x16x32_bf16(af[mi], bfr[ni], acc[mi][ni], 0,0,0);
    __syncthreads();
  }
  #pragma unroll
  for (int mi=0; mi<MT; ++mi){
    const int rb = m0 + wm*MT*16 + mi*16 + quad*4;
    #pragma unroll
    for (int ni=0; ni<NT; ++ni){
      const int col = n0 + wn*NT*16 + ni*16 + l15;
      #pragma unroll
      for (int r=0; r<4; ++r){
        float v = acc[mi][ni][r];
        size_t idx = (size_t)(rb + r)*N + col;
        if constexpr (OF32) Cf[idx] = v;
        if constexpr (OB16) Cb[idx] = f2b(v);
      }
    }
  }
}

// ---------------- rowsum of 64 contiguous fp32 per output ----------------
__global__ __launch_bounds__(256)
void k_rowsum64(const float* __restrict__ src, float* __restrict__ dst, int n, int stride){
  int i = blockIdx.x*256 + threadIdx.x;
  if (i >= n) return;
  const float4* p = (const float4*)(src + (size_t)i*stride);
  float s = 0.f;
  #pragma unroll
  for (int j=0;j<16;++j){ float4 v = p[j]; s += v.x+v.y+v.z+v.w; }
  dst[i] = s;
}

// ---------------- V_exp^T[h][d][t] = sum_l latent_v[t,l]*v_up[h,l,d] ----------------
__global__ __launch_bounds__(64)
void k_vexp(const float* __restrict__ lkvf, const float* __restrict__ vup,
            ushort* __restrict__ vexpT){
  const int h = blockIdx.y, t0 = blockIdx.x*64, tid = threadIdx.x;
  __shared__ float lvs[64][65];      // latent_v tile (pad: no bank conflict)
  __shared__ float vups[64][128];    // v_up[h] (broadcast reads)
  for (int c = tid; c < 64*64; c += 64){
    int row = c>>6, col = c&63;
    lvs[row][col] = lkvf[(size_t)(t0+row)*128 + 64 + col];   // V half of fused KV
  }
  for (int c = tid; c < 64*128; c += 64)
    vups[c>>7][c&127] = vup[(size_t)h*L_*D_ + c];
  __syncthreads();
  for (int dc=0; dc<128; dc+=32){
    float acc[32] = {};
    for (int l=0;l<64;++l){
      float a = lvs[tid][l];
      #pragma unroll
      for (int d=0;d<32;++d) acc[d] += a*vups[l][dc+d];
    }
    #pragma unroll
    for (int d=0;d<32;++d)
      vexpT[((size_t)h*D_ + dc+d)*T_ + t0 + tid] = f2b(acc[d]);  // coalesced over t
  }
}

// ---------------- flash attention: one (head, 64-row Q tile) per block ----------------
__global__ __launch_bounds__(256)
void k_attn(const ushort* __restrict__ qlat,   // [T, H*64] bf16
            const ushort* __restrict__ lkv,    // [T, 128]  bf16 (cols 0..63 = latent_k)
            const float*  __restrict__ rsq,    // [T, H]
            const float*  __restrict__ rsk,    // [T]
            const ushort* __restrict__ vexpT,  // [H][128][T] bf16
            ushort*       __restrict__ ctx){   // [T, 2048] bf16
  const int h  = blockIdx.y;
  const int t0 = ((int)gridDim.x - 1 - (int)blockIdx.x)*64;  // heavy tiles first
  const int tid = threadIdx.x, lane = tid & 63, w = tid >> 6;
  const int l15 = lane & 15, quad = lane >> 4;
  constexpr int LP = 72;   // padded stride: 144B rows, 16B aligned, 2-way banks
  __shared__ ushort Qs[64*LP], Ks[64*LP], Ps[64*LP];
  __shared__ ushort Vts[128*LP];

  for (int c = tid; c < 512; c += 256){
    int row = c>>3, kc = (c&7)*8;
    *(uint4*)(&Qs[row*LP+kc]) = *(const uint4*)(qlat + (size_t)(t0+row)*(H_*64) + h*64 + kc);
  }
  const float isl = 0.125f;            // 1/sqrt(L)
  float mrow[4], lrow[4], rq[4], alpha[4];
  floatx4 o[8] = {};
  #pragma unroll
  for (int r=0;r<4;++r){
    mrow[r] = -1e30f; lrow[r] = 0.f;
    rq[r] = rsq[(size_t)(t0 + w*16 + quad*4 + r)*H_ + h] * (0.5f*isl);  // alpha*isl*rowsum_q
  }
  const int ns = t0/64 + 1;
  for (int st=0; st<ns; ++st){
    const int s0 = st*64;
    __syncthreads();                                   // protect K/V LDS from prior reads
    for (int c = tid; c < 512; c += 256){
      int row=c>>3, kc=(c&7)*8;
      *(uint4*)(&Ks[row*LP+kc]) = *(const uint4*)(lkv + (size_t)(s0+row)*128 + kc);
    }
    for (int c = tid; c < 1024; c += 256){
      int d=c>>3, ss=(c&7)*8;
      *(uint4*)(&Vts[d*LP+ss]) = *(const uint4*)(vexpT + ((size_t)h*D_ + d)*T_ + s0 + ss);
    }
    __syncthreads();
    // ---- S = Q K^T (wave w: rows w*16..w*16+15) ----
    floatx4 accs[4] = {};
    #pragma unroll
    for (int kk=0;kk<64;kk+=32){
      bf16x8 a = *(const bf16x8*)(&Qs[(w*16+l15)*LP + kk + quad*8]);
      #pragma unroll
      for (int jt=0;jt<4;++jt){
        bf16x8 b = *(const bf16x8*)(&Ks[(jt*16+l15)*LP + kk + quad*8]);
        accs[jt] = __builtin_amdgcn_mfma_f32_16x16x32_bf16(a, b, accs[jt], 0,0,0);
      }
    }
    // ---- mask + rank-1 band + online softmax ----
    float rkc[4], pv[4][4];
    #pragma unroll
    for (int jt=0;jt<4;++jt) rkc[jt] = rsk[s0 + jt*16 + l15];
    #pragma unroll
    for (int r=0;r<4;++r){
      const int row = t0 + w*16 + quad*4 + r;
      float svr[4], mloc = -1e30f;
      #pragma unroll
      for (int jt=0;jt<4;++jt){
        int col = s0 + jt*16 + l15;
        int dd = row - col;
        float x = accs[jt][r]*isl;
        if (dd < 0) x = -1e30f;                 // causal
        else if (dd <= 64) x += rq[r]*rkc[jt];  // reciprocal band (rank-1)
        svr[jt] = x; mloc = fmaxf(mloc, x);
      }
      #pragma unroll
      for (int off=1; off<16; off<<=1) mloc = fmaxf(mloc, __shfl_xor(mloc, off));
      float mn = fmaxf(mrow[r], mloc);
      float al = __expf(mrow[r]-mn);
      float s = 0.f;
      #pragma unroll
      for (int jt=0;jt<4;++jt){ float p = __expf(svr[jt]-mn); pv[jt][r]=p; s+=p; }
      #pragma unroll
      for (int off=1; off<16; off<<=1) s += __shfl_xor(s, off);
      lrow[r] = lrow[r]*al + s; mrow[r] = mn; alpha[r] = al;
    }
    // ---- P (C-layout) -> LDS -> A-layout; wave-private band ----
    #pragma unroll
    for (int jt=0;jt<4;++jt)
      #pragma unroll
      for (int r=0;r<4;++r)
        Ps[(w*16+quad*4+r)*LP + jt*16 + l15] = f2b(pv[jt][r]);
    #pragma unroll
    for (int nt=0;nt<8;++nt)
      #pragma unroll
      for (int r=0;r<4;++r) o[nt][r] *= alpha[r];
    __syncthreads();                                   // safe P write->read ordering
    // ---- O += P @ V ----
    #pragma unroll
    for (int kk=0;kk<64;kk+=32){
      bf16x8 ap = *(const bf16x8*)(&Ps[(w*16+l15)*LP + kk + quad*8]);
      #pragma unroll
      for (int nt=0;nt<8;++nt){
        bf16x8 bv = *(const bf16x8*)(&Vts[(nt*16+l15)*LP + kk + quad*8]);
        o[nt] = __builtin_amdgcn_mfma_f32_16x16x32_bf16(ap, bv, o[nt], 0,0,0);
      }
    }
  }
  #pragma unroll
  for (int r=0;r<4;++r){
    float inv = 1.f/lrow[r];
    const int row = t0 + w*16 + quad*4 + r;
    #pragma unroll
    for (int nt=0;nt<8;++nt)
      ctx[(size_t)row*E_ + h*D_ + nt*16 + l15] = f2b(o[nt][r]*inv);
  }
}

// ---------------- launch ----------------
extern "C" void kernel_launch(void* const* d_in, const int* in_sizes, int n_in,
                              void* d_out, int out_size, void* d_ws, size_t ws_size,
                              hipStream_t stream) {
  const float* hs  = (const float*)d_in[0];
  const float* Wq  = (const float*)d_in[1];
  const float* Wk  = (const float*)d_in[2];
  const float* Wv  = (const float*)d_in[3];
  const float* q2l = (const float*)d_in[4];
  const float* vup = (const float*)d_in[5];
  const float* Wo  = (const float*)d_in[6];
  float* out = (float*)d_out;
  char* ws = (char*)d_ws;

  // workspace layout (bytes), ~50.2 MB total
  ushort* hsb   = (ushort*)(ws + 0);          // [2048][2048] bf16
  ushort* Wkvb  = (ushort*)(ws + 8388608);    // [128][2048]  bf16 (Wk rows 0..63, Wv rows 64..127)
  ushort* Wob   = (ushort*)(ws + 8912896);    // [2048][2048] bf16
  ushort* Wqlb  = (ushort*)(ws + 17301504);   // [1024][2048] bf16
  float*  qlf   = (float*) (ws + 21495808);   // [2048][1024] fp32 q_latent
  ushort* qlb   = (ushort*)(ws + 29884416);   // [2048][1024] bf16 q_latent
  float*  lkvf  = (float*) (ws + 34078720);   // [2048][128]  fp32 (k | v)
  ushort* lkvb  = (ushort*)(ws + 35127296);   // [2048][128]  bf16
  float*  rsqp  = (float*) (ws + 35651584);   // [2048][16]
  float*  rskp  = (float*) (ws + 35782656);   // [2048]
  ushort* vexpT = (ushort*)(ws + 35790848);   // [16][128][2048] bf16
  ushort* ctxb  = (ushort*)(ws + 44179456);   // [2048][2048] bf16

  // 1) bf16 conversions
  k_f2b<<<4096, 256, 0, stream>>>(hs, hsb, T_*E_);
  k_f2b<<<128,  256, 0, stream>>>(Wk, Wkvb,            L_*E_);
  k_f2b<<<128,  256, 0, stream>>>(Wv, Wkvb + L_*E_,    L_*E_);
  k_f2b<<<4096, 256, 0, stream>>>(Wo, Wob, E_*E_);

  // 2) fold q_to_latent into Wq
  k_prep_wql<<<dim3(16,8,16), 128, 0, stream>>>(Wq, q2l, Wqlb);

  // 3) q_latent = hs @ Wql^T   [2048,1024]  (fp32 + bf16)
  gemm_bt<2,2,4,2,true,true><<<dim3(16,16), 256, 0, stream>>>(hsb, Wqlb, qlf, qlb, T_, 1024, E_);

  // 4) latent k|v = hs @ [Wk;Wv]^T  [2048,128]
  gemm_bt<2,2,2,2,true,true><<<dim3(2,32), 256, 0, stream>>>(hsb, Wkvb, lkvf, lkvb, T_, 128, E_);

  // 5) rowsums for the rank-1 reciprocal band
  k_rowsum64<<<128, 256, 0, stream>>>(qlf,  rsqp, T_*H_, 64);
  k_rowsum64<<<8,   256, 0, stream>>>(lkvf, rskp, T_,    128);

  // 6) V_exp^T[h][d][t]
  k_vexp<<<dim3(32,16), 64, 0, stream>>>(lkvf, vup, vexpT);

  // 7) flash attention -> ctx bf16
  k_attn<<<dim3(32,16), 256, 0, stream>>>(qlb, lkvb, rsqp, rskp, vexpT, ctxb);

  // 8) out = ctx @ Wo^T  (fp32 to d_out)
  gemm_bt<2,2,4,4,true,false><<<dim3(16,16), 256, 0, stream>>>(ctxb, Wob, out, nullptr, T_, E_, E_);
}

// Round 2
// 387.177 us; speedup vs baseline: 1.1364x; 1.1364x over previous
//
#include <hip/hip_runtime.h>

// RA_MLA_Attention — MI355X (gfx950). Round 1.
// B=1, T=2048, E=2048, H=16, D=128, L=64, RA_WINDOW=64, RA_ALPHA=0.5
//
// Algebra:
//   logits_recip[t,s] = rowsum_l(q_latent[t,h,:]) * rowsum_l(latent_k[s,:])  (rank-1)
//   q_latent = hs @ Wql^T,  Wql[(h,l),e] = sum_d q2l[h,d,l]*Wq[h*128+d,e]
// Round-1 changes vs round 0:
//   * k_attn rewritten: S^T MFMA layout (lane owns one q-row -> 2-step quad
//     reduction), log2-domain softmax (isl*log2e folded into qlb), 2 cheap
//     barriers/tile with register-prefetch staging (loads issued after the
//     drain barrier, land during compute), LDS stride 88 (even bank tiling),
//     Q frags direct from global, P round-trip is wave-private (no barrier).
//   * big GEMMs use global_load_lds width-16 staging (m97 pattern).
//   * k_prep_wql: one pass over Wq, scalar q2l loads.

#define T_ 2048
#define E_ 2048
#define H_ 16
#define D_ 128
#define L_ 64

typedef float  floatx4 __attribute__((ext_vector_type(4)));
typedef __bf16 bf16x8  __attribute__((ext_vector_type(8)));

__device__ __forceinline__ ushort f2b(float x){           // fp32 -> bf16 bits, RNE
  unsigned int u = __float_as_uint(x);
  u = (u + 0x7fffu + ((u >> 16) & 1u)) >> 16;
  return (ushort)u;
}

__device__ __forceinline__ void glds16(const ushort* g, ushort* l){
#if __has_builtin(__builtin_amdgcn_global_load_lds)
  __builtin_amdgcn_global_load_lds((const __attribute__((address_space(1))) void*)g,
                                   (__attribute__((address_space(3))) void*)l, 16, 0, 0);
#else
  *(uint4*)l = *(const uint4*)g;    // sync fallback (correct, slower)
#endif
}

// ---------------- fp32 -> bf16 convert ----------------
__global__ __launch_bounds__(256)
void k_f2b(const float* __restrict__ in, ushort* __restrict__ out, int n){
  int i = (blockIdx.x*256 + threadIdx.x)*4;
  if (i < n){
    float4 v = *(const float4*)(in + i);
    ushort4 o; o.x=f2b(v.x); o.y=f2b(v.y); o.z=f2b(v.z); o.w=f2b(v.w);
    *(ushort4*)(out + i) = o;
  }
}

// ---------------- fold q_to_latent into Wq:  Wql[(h,l),e] ----------------
// One pass over Wq (no re-read); q2l read via uniform (scalar) loads.
__global__ __launch_bounds__(128)
void k_prep_wql(const float* __restrict__ Wq, const float* __restrict__ q2l,
                ushort* __restrict__ Wql){
  const int h = blockIdx.z, lh = blockIdx.y;            // l half: lh*32..lh*32+31
  const int e = blockIdx.x*128 + threadIdx.x;
  const float* qb = q2l + (size_t)h*D_*L_ + lh*32;      // [d][l'] stride 64
  float acc[32];
  #pragma unroll
  for (int i=0;i<32;++i) acc[i]=0.f;
  for (int d=0; d<128; ++d){
    float wv = Wq[(size_t)(h*128+d)*E_ + e];            // coalesced vector load
    #pragma unroll
    for (int i=0;i<32;++i) acc[i] += wv*qb[(size_t)d*64 + i];  // uniform -> SGPR
  }
  #pragma unroll
  for (int i=0;i<32;++i) Wql[(size_t)(h*64 + lh*32 + i)*E_ + e] = f2b(acc[i]);
}

// ---------------- legacy GEMM (VGPR staging) for the small lkv GEMM ----------
template<int WGM,int WGN,int MT,int NT,bool OF32,bool OB16>
__global__ __launch_bounds__(WGM*WGN*64)
void gemm_bt(const ushort* __restrict__ A, const ushort* __restrict__ B,
             float* __restrict__ Cf, ushort* __restrict__ Cb,
             int M, int N, int K, float scale){
  constexpr int BM = WGM*MT*16, BN = WGN*NT*16, BK = 32;
  constexpr int NTHR = WGM*WGN*64;
  constexpr int LDT = BK + 8;
  __shared__ ushort As[BM*LDT];
  __shared__ ushort Bs[BN*LDT];
  const int tid = threadIdx.x, lane = tid & 63, wv = tid >> 6;
  const int wm = wv % WGM, wn = wv / WGM;
  const int l15 = lane & 15, quad = lane >> 4;
  const int m0 = blockIdx.y*BM, n0 = blockIdx.x*BN;
  floatx4 acc[MT][NT] = {};
  for (int k0 = 0; k0 < K; k0 += BK){
    #pragma unroll
    for (int c = tid; c < BM*BK/8; c += NTHR){
      int row = c >> 2, kc = (c & 3)*8;
      *(uint4*)(&As[row*LDT + kc]) = *(const uint4*)(A + (size_t)(m0+row)*K + k0 + kc);
    }
    #pragma unroll
    for (int c = tid; c < BN*BK/8; c += NTHR){
      int row = c >> 2, kc = (c & 3)*8;
      *(uint4*)(&Bs[row*LDT + kc]) = *(const uint4*)(B + (size_t)(n0+row)*K + k0 + kc);
    }
    __syncthreads();
    bf16x8 af[MT], bfr[NT];
    #pragma unroll
    for (int mi=0; mi<MT; ++mi)
      af[mi] = *(const bf16x8*)(&As[(wm*MT*16 + mi*16 + l15)*LDT + quad*8]);
    #pragma unroll
    for (int ni=0; ni<NT; ++ni)
      bfr[ni] = *(const bf16x8*)(&Bs[(wn*NT*16 + ni*16 + l15)*LDT + quad*8]);
    #pragma unroll
    for (int mi=0; mi<MT; ++mi)
      #pragma unroll
      for (int ni=0; ni<NT; ++ni)
        acc[mi][ni] = __builtin_amdgcn_mfma_f32_16x16x32_bf16(af[mi], bfr[ni], acc[mi][ni], 0,0,0);
    __syncthreads();
  }
  #pragma unroll
  for (int mi=0; mi<MT; ++mi){
    const int rb = m0 + wm*MT*16 + mi*16 + quad*4;
    #pragma unroll
    for (int ni=0; ni<NT; ++ni){
      const int col = n0 + wn*NT*16 + ni*16 + l15;
      #pragma unroll
      for (int r=0; r<4; ++r){
        float v = acc[mi][ni][r];
        size_t idx = (size_t)(rb + r)*N + col;
        if constexpr (OF32) Cf[idx] = v;
        if constexpr (OB16) Cb[idx] = f2b(v*scale);
      }
    }
  }
}

// ---------------- m97-style GEMM: global_load_lds staging, unpadded LDS -------
// 4 waves (2x2), wave tile MT x NT of 16; BM=32*MT, BN=32*NT.
template<int MT,int NT,bool OF32,bool OB16>
__global__ __launch_bounds__(256)
void gemm_glds(const ushort* __restrict__ A, const ushort* __restrict__ B,
               float* __restrict__ Cf, ushort* __restrict__ Cb,
               int M, int N, int K, float scale){
  constexpr int BM = 32*MT, BN = 32*NT;
  constexpr int IA = BM/64, IB = BN/64;     // wave-issues per tile
  __shared__ ushort As[BM*32];
  __shared__ ushort Bs[BN*32];
  const int tid = threadIdx.x, lane = tid&63, wv = tid>>6;
  const int wm = wv & 1, wn = wv >> 1;
  const int l15 = lane&15, quad = lane>>4;
  const int m0 = blockIdx.y*BM, n0 = blockIdx.x*BN;
  floatx4 acc[MT][NT] = {};
  for (int k0=0; k0<K; k0+=32){
    __syncthreads();                               // prev-iter LDS reads done
    #pragma unroll
    for (int j=0;j<IA;++j){
      int c = (j*4 + wv)*64 + lane;                // 16B chunk id, wave-contiguous
      int row = c>>2, kc = (c&3)*8;
      glds16(A + (size_t)(m0+row)*K + k0 + kc, &As[c*8]);
    }
    #pragma unroll
    for (int j=0;j<IB;++j){
      int c = (j*4 + wv)*64 + lane;
      int row = c>>2, kc = (c&3)*8;
      glds16(B + (size_t)(n0+row)*K + k0 + kc, &Bs[c*8]);
    }
    __syncthreads();                               // vmcnt(0) drain -> staged
    bf16x8 af[MT], bfr[NT];
    #pragma unroll
    for (int mi=0;mi<MT;++mi)
      af[mi] = *(const bf16x8*)(&As[(wm*MT*16 + mi*16 + l15)*32 + quad*8]);
    #pragma unroll
    for (int ni=0;ni<NT;++ni)
      bfr[ni] = *(const bf16x8*)(&Bs[(wn*NT*16 + ni*16 + l15)*32 + quad*8]);
    #pragma unroll
    for (int mi=0;mi<MT;++mi)
      #pragma unroll
      for (int ni=0;ni<NT;++ni)
        acc[mi][ni] = __builtin_amdgcn_mfma_f32_16x16x32_bf16(af[mi], bfr[ni], acc[mi][ni], 0,0,0);
  }
  #pragma unroll
  for (int mi=0;mi<MT;++mi){
    const int rb = m0 + wm*MT*16 + mi*16 + quad*4;
    #pragma unroll
    for (int ni=0;ni<NT;++ni){
      const int col = n0 + wn*NT*16 + ni*16 + l15;
      #pragma unroll
      for (int r=0;r<4;++r){
        float v = acc[mi][ni][r];
        size_t idx = (size_t)(rb + r)*N + col;
        if constexpr (OF32) Cf[idx] = v;
        if constexpr (OB16) Cb[idx] = f2b(v*scale);
      }
    }
  }
}

// ---------------- rowsum of 64 contiguous fp32 per output ----------------
__global__ __launch_bounds__(256)
void k_rowsum64(const float* __restrict__ src, float* __restrict__ dst, int n, int stride){
  int i = blockIdx.x*256 + threadIdx.x;
  if (i >= n) return;
  const float4* p = (const float4*)(src + (size_t)i*stride);
  float s = 0.f;
  #pragma unroll
  for (int j=0;j<16;++j){ float4 v = p[j]; s += v.x+v.y+v.z+v.w; }
  dst[i] = s;
}

// ---------------- V_exp^T[h][d][t] = sum_l latent_v[t,l]*v_up[h,l,d] ----------------
__global__ __launch_bounds__(64)
void k_vexp(const float* __restrict__ lkvf, const float* __restrict__ vup,
            ushort* __restrict__ vexpT){
  const int h = blockIdx.y, t0 = blockIdx.x*64, tid = threadIdx.x;
  __shared__ float lvs[64][65];
  __shared__ float vups[64][128];
  for (int c = tid; c < 64*64; c += 64){
    int row = c>>6, col = c&63;
    lvs[row][col] = lkvf[(size_t)(t0+row)*128 + 64 + col];
  }
  for (int c = tid; c < 64*128; c += 64)
    vups[c>>7][c&127] = vup[(size_t)h*L_*D_ + c];
  __syncthreads();
  for (int dc=0; dc<128; dc+=32){
    float acc[32] = {};
    for (int l=0;l<64;++l){
      float a = lvs[tid][l];
      #pragma unroll
      for (int d=0;d<32;++d) acc[d] += a*vups[l][dc+d];
    }
    #pragma unroll
    for (int d=0;d<32;++d)
      vexpT[((size_t)h*D_ + dc+d)*T_ + t0 + tid] = f2b(acc[d]);
  }
}

// ---------------- flash attention (S^T layout, log2 softmax) ----------------
// Block = 4 waves, (head, 64-row Q tile). Wave w owns rows t0+w*16..+15.
// Q is pre-scaled by isl*log2e, so S^T accs are log2-domain logits.
// Per tile: 2 barriers; prefetch loads issued after barrier B land during compute.
__global__ __launch_bounds__(256)
void k_attn(const ushort* __restrict__ qlat,   // [T][1024] bf16, pre-scaled
            const ushort* __restrict__ lkv,    // [T][128]  bf16 (cols 0..63 = K)
            const float*  __restrict__ rsq,    // [T][16]
            const float*  __restrict__ rsk,    // [T]
            const ushort* __restrict__ vexpT,  // [16][128][T] bf16
            ushort*       __restrict__ ctx){   // [T][2048] bf16
  constexpr int LP = 88;                       // 176B rows: 16B aligned, even bank tiling
  __shared__ ushort Ks[64*LP];
  __shared__ ushort Vts[128*LP];
  __shared__ ushort Ps[4*16*LP];
  __shared__ float  rsks[64];
  const int h  = blockIdx.y;
  const int qt = (int)gridDim.x - 1 - (int)blockIdx.x;   // heavy tiles first
  const int t0 = qt*64;
  const int tid = threadIdx.x, lane = tid & 63, w = tid >> 6;
  const int l15 = lane & 15, quad = lane >> 4;

  // per-wave-constant Q fragments (B-operand: n=q, k=latent), direct from global
  const int qrow = t0 + w*16 + l15;
  const bf16x8 q0 = *(const bf16x8*)(qlat + (size_t)qrow*1024 + h*64 + quad*8);
  const bf16x8 q1 = *(const bf16x8*)(qlat + (size_t)qrow*1024 + h*64 + 32 + quad*8);
  const float rqv = rsq[(size_t)qrow*H_ + h] * 0.09016844f;  // 0.5*isl*log2e

  float mrun = -INFINITY, lrun = 0.f;
  floatx4 o[8] = {};
  uint4 kreg[2], vreg[4]; float4 rr;

  // prologue: load tile 0 into registers
  #pragma unroll
  for (int j=0;j<2;++j){ int c = tid + j*256;
    kreg[j] = *(const uint4*)(lkv + (size_t)(c>>3)*128 + (c&7)*8); }
  #pragma unroll
  for (int j=0;j<4;++j){ int c = tid + j*256;
    vreg[j] = *(const uint4*)(vexpT + ((size_t)h*128 + (c>>3))*T_ + (c&7)*8); }
  if (tid < 16) rr = *(const float4*)(rsk + tid*4);

  for (int st=0; st<=qt; ++st){
    __syncthreads();                                   // A: prev compute reads done
    #pragma unroll
    for (int j=0;j<2;++j){ int c = tid + j*256;
      *(uint4*)(&Ks[(c>>3)*LP + (c&7)*8]) = kreg[j]; }
    #pragma unroll
    for (int j=0;j<4;++j){ int c = tid + j*256;
      *(uint4*)(&Vts[(c>>3)*LP + (c&7)*8]) = vreg[j]; }
    if (tid < 16) *(float4*)(&rsks[tid*4]) = rr;
    __syncthreads();                                   // B: stores visible (cheap)
    if (st < qt){                                      // prefetch next tile (async)
      const int s1 = (st+1)*64;
      #pragma unroll
      for (int j=0;j<2;++j){ int c = tid + j*256;
        kreg[j] = *(const uint4*)(lkv + (size_t)(s1 + (c>>3))*128 + (c&7)*8); }
      #pragma unroll
      for (int j=0;j<4;++j){ int c = tid + j*256;
        vreg[j] = *(const uint4*)(vexpT + ((size_t)h*128 + (c>>3))*T_ + s1 + (c&7)*8); }
      if (tid < 16) rr = *(const float4*)(rsk + s1 + tid*4);
    }
    const int s0 = st*64;
    // ---- S^T = K Q^T : C[s,q], lane owns q=l15, s=jt*16+quad*4+r ----
    floatx4 sT[4] = {};
    #pragma unroll
    for (int jt=0;jt<4;++jt){
      bf16x8 k0f = *(const bf16x8*)(&Ks[(jt*16+l15)*LP + quad*8]);
      sT[jt] = __builtin_amdgcn_mfma_f32_16x16x32_bf16(k0f, q0, sT[jt], 0,0,0);
      bf16x8 k1f = *(const bf16x8*)(&Ks[(jt*16+l15)*LP + 32 + quad*8]);
      sT[jt] = __builtin_amdgcn_mfma_f32_16x16x32_bf16(k1f, q1, sT[jt], 0,0,0);
    }
    // ---- mask + rank-1 band + online softmax (log2 domain) ----
    float xs[16], pr[16];
    float mloc = -3.0e38f;
    #pragma unroll
    for (int jt=0;jt<4;++jt){
      const float4 rk4 = *(const float4*)(&rsks[jt*16 + quad*4]);   // broadcast read
      #pragma unroll
      for (int r=0;r<4;++r){
        const int sg = s0 + jt*16 + quad*4 + r;
        const int dd = qrow - sg;
        float x = sT[jt][r];
        x = (dd <= 64) ? x + rqv*((const float*)&rk4)[r] : x;   // band add
        x = (dd < 0)   ? -3.0e38f : x;                          // causal mask
        xs[jt*4+r] = x; mloc = fmaxf(mloc, x);
      }
    }
    mloc = fmaxf(mloc, __shfl_xor(mloc, 16));
    mloc = fmaxf(mloc, __shfl_xor(mloc, 32));
    const float mn = fmaxf(mrun, mloc);
    const float al = exp2f(mrun - mn);
    float ss = 0.f;
    #pragma unroll
    for (int i=0;i<16;++i){ float p = exp2f(xs[i]-mn); pr[i]=p; ss+=p; }
    ss += __shfl_xor(ss, 16); ss += __shfl_xor(ss, 32);
    lrun = lrun*al + ss; mrun = mn;
    // ---- P write (wave-private region; same-wave DS ordering, no barrier) ----
    #pragma unroll
    for (int jt=0;jt<4;++jt){
      ushort4 pw; pw.x=f2b(pr[jt*4]); pw.y=f2b(pr[jt*4+1]);
      pw.z=f2b(pr[jt*4+2]); pw.w=f2b(pr[jt*4+3]);
      *(ushort4*)(&Ps[(w*16+l15)*LP + jt*16 + quad*4]) = pw;
    }
    // ---- rescale O rows (alpha lives at lane quad*4+r) ----
    float alr[4];
    #pragma unroll
    for (int r=0;r<4;++r) alr[r] = __shfl(al, quad*4 + r);
    #pragma unroll
    for (int nt=0;nt<8;++nt){
      o[nt][0]*=alr[0]; o[nt][1]*=alr[1]; o[nt][2]*=alr[2]; o[nt][3]*=alr[3];
    }
    // ---- O += P V ----
    #pragma unroll
    for (int kks=0;kks<2;++kks){
      bf16x8 pf = *(const bf16x8*)(&Ps[(w*16+l15)*LP + kks*32 + quad*8]);
      #pragma unroll
      for (int nt=0;nt<8;++nt){
        bf16x8 vf = *(const bf16x8*)(&Vts[(nt*16+l15)*LP + kks*32 + quad*8]);
        o[nt] = __builtin_amdgcn_mfma_f32_16x16x32_bf16(pf, vf, o[nt], 0,0,0);
      }
    }
  }
  // ---- epilogue: normalize, write ctx ----
  const float linv = 1.f/lrun;
  float lr4[4];
  #pragma unroll
  for (int r=0;r<4;++r) lr4[r] = __shfl(linv, quad*4 + r);
  #pragma unroll
  for (int r=0;r<4;++r){
    const int row = t0 + w*16 + quad*4 + r;
    #pragma unroll
    for (int nt=0;nt<8;++nt)
      ctx[(size_t)row*E_ + h*D_ + nt*16 + l15] = f2b(o[nt][r]*lr4[r]);
  }
}

// ---------------- launch ----------------
extern "C" void kernel_launch(void* const* d_in, const int* in_sizes, int n_in,
                              void* d_out, int out_size, void* d_ws, size_t ws_size,
                              hipStream_t stream) {
  const float* hs  = (const float*)d_in[0];
  const float* Wq  = (const float*)d_in[1];
  const float* Wk  = (const float*)d_in[2];
  const float* Wv  = (const float*)d_in[3];
  const float* q2l = (const float*)d_in[4];
  const float* vup = (const float*)d_in[5];
  const float* Wo  = (const float*)d_in[6];
  float* out = (float*)d_out;
  char* ws = (char*)d_ws;

  // workspace layout (bytes), ~52 MB total
  ushort* hsb   = (ushort*)(ws + 0);          // [2048][2048] bf16
  ushort* Wkvb  = (ushort*)(ws + 8388608);    // [128][2048]  bf16 (Wk|Wv)
  ushort* Wob   = (ushort*)(ws + 8912896);    // [2048][2048] bf16
  ushort* Wqlb  = (ushort*)(ws + 17301504);   // [1024][2048] bf16
  float*  qlf   = (float*) (ws + 21495808);   // [2048][1024] fp32 q_latent (raw)
  ushort* qlb   = (ushort*)(ws + 29884416);   // [2048][1024] bf16 q_latent * isl*log2e
  float*  lkvf  = (float*) (ws + 34078720);   // [2048][128]  fp32 (k | v)
  ushort* lkvb  = (ushort*)(ws + 35127296);   // [2048][128]  bf16
  float*  rsqp  = (float*) (ws + 35651584);   // [2048][16]
  float*  rskp  = (float*) (ws + 35782656);   // [2048]
  ushort* vexpT = (ushort*)(ws + 35790848);   // [16][128][2048] bf16
  ushort* ctxb  = (ushort*)(ws + 44179456);   // [2048][2048] bf16

  // 1) bf16 conversions
  k_f2b<<<4096, 256, 0, stream>>>(hs, hsb, T_*E_);
  k_f2b<<<128,  256, 0, stream>>>(Wk, Wkvb,            L_*E_);
  k_f2b<<<128,  256, 0, stream>>>(Wv, Wkvb + L_*E_,    L_*E_);
  k_f2b<<<4096, 256, 0, stream>>>(Wo, Wob, E_*E_);

  // 2) fold q_to_latent into Wq
  k_prep_wql<<<dim3(16,2,16), 128, 0, stream>>>(Wq, q2l, Wqlb);

  // 3) q_latent = hs @ Wql^T  [2048,1024]; bf16 copy pre-scaled by isl*log2e
  gemm_glds<2,2,true,true><<<dim3(16,32), 256, 0, stream>>>(
      hsb, Wqlb, qlf, qlb, T_, 1024, E_, 0.18033688f);

  // 4) latent k|v = hs @ [Wk;Wv]^T  [2048,128]
  gemm_bt<2,2,2,2,true,true><<<dim3(2,32), 256, 0, stream>>>(
      hsb, Wkvb, lkvf, lkvb, T_, 128, E_, 1.0f);

  // 5) rowsums for the rank-1 reciprocal band
  k_rowsum64<<<128, 256, 0, stream>>>(qlf,  rsqp, T_*H_, 64);
  k_rowsum64<<<8,   256, 0, stream>>>(lkvf, rskp, T_,    128);

  // 6) V_exp^T[h][d][t]
  k_vexp<<<dim3(32,16), 64, 0, stream>>>(lkvf, vup, vexpT);

  // 7) flash attention -> ctx bf16
  k_attn<<<dim3(32,16), 256, 0, stream>>>(qlb, lkvb, rsqp, rskp, vexpT, ctxb);

  // 8) out = ctx @ Wo^T  (fp32 to d_out)
  gemm_glds<4,2,true,false><<<dim3(32,16), 256, 0, stream>>>(
      ctxb, Wob, out, nullptr, T_, E_, E_, 1.0f);
}

// Round 3
// 328.481 us; speedup vs baseline: 1.3395x; 1.1787x over previous
//
#include <hip/hip_runtime.h>

// RA_MLA_Attention — MI355X (gfx950). Round 2.
// B=1, T=2048, E=2048, H=16, D=128, L=64, RA_WINDOW=64, RA_ALPHA=0.5
//
// Round-2 changes:
//   * k_attn split-S (flash-decoding): block = (head, 64-row Q-tile, 8-S-tile
//     chunk) -> 1280 blocks (was 512), max 8 serial tiles (was 32), LP=72
//     (37KB LDS -> 3 blocks/CU). Partials merged by k_merge. Non-diagonal
//     tiles skip band/mask. Fallback to unsplit if ws_size too small.
//   * latent k|v GEMM fused into q_latent GEMM (one N=1152 bf16-out GEMM).
//   * V_exp as register-only MFMA kernel (k_vexp_mfma) + vupT prep.
//   * rowsums from bf16 outputs (no fp32 GEMM outputs at all).

#define T_ 2048
#define E_ 2048
#define H_ 16
#define D_ 128
#define L_ 64
#define NQ 1152            // fused qkv GEMM N (1024 ql | 64 k | 64 v)

typedef float  floatx4 __attribute__((ext_vector_type(4)));
typedef __bf16 bf16x8  __attribute__((ext_vector_type(8)));

__device__ __forceinline__ ushort f2b(float x){           // fp32 -> bf16 bits, RNE
  unsigned int u = __float_as_uint(x);
  u = (u + 0x7fffu + ((u >> 16) & 1u)) >> 16;
  return (ushort)u;
}
__device__ __forceinline__ float b2f(ushort u){
  return __uint_as_float(((unsigned int)u) << 16);
}

__device__ __forceinline__ void glds16(const ushort* g, ushort* l){
#if __has_builtin(__builtin_amdgcn_global_load_lds)
  __builtin_amdgcn_global_load_lds((const __attribute__((address_space(1))) void*)g,
                                   (__attribute__((address_space(3))) void*)l, 16, 0, 0);
#else
  *(uint4*)l = *(const uint4*)g;
#endif
}

// ---------------- fp32 -> bf16 convert ----------------
__global__ __launch_bounds__(256)
void k_f2b(const float* __restrict__ in, ushort* __restrict__ out, int n){
  int i = (blockIdx.x*256 + threadIdx.x)*4;
  if (i < n){
    float4 v = *(const float4*)(in + i);
    ushort4 o; o.x=f2b(v.x); o.y=f2b(v.y); o.z=f2b(v.z); o.w=f2b(v.w);
    *(ushort4*)(out + i) = o;
  }
}

// ---------------- fold q_to_latent into Wq:  Wql[(h,l),e] (rows of Wqkvb) ----
__global__ __launch_bounds__(128)
void k_prep_wql(const float* __restrict__ Wq, const float* __restrict__ q2l,
                ushort* __restrict__ Wql){
  const int h = blockIdx.z, lh = blockIdx.y;            // l half: lh*32..lh*32+31
  const int e = blockIdx.x*128 + threadIdx.x;
  const float* qb = q2l + (size_t)h*D_*L_ + lh*32;
  float acc[32];
  #pragma unroll
  for (int i=0;i<32;++i) acc[i]=0.f;
  for (int d=0; d<128; ++d){
    float wv = Wq[(size_t)(h*128+d)*E_ + e];
    #pragma unroll
    for (int i=0;i<32;++i) acc[i] += wv*qb[(size_t)d*64 + i];
  }
  #pragma unroll
  for (int i=0;i<32;++i) Wql[(size_t)(h*64 + lh*32 + i)*E_ + e] = f2b(acc[i]);
}

// ---------------- vupT[h][d][l] = vup[h][l][d], bf16 ----------------
__global__ __launch_bounds__(256)
void k_prep_vupT(const float* __restrict__ vup, ushort* __restrict__ vupT){
  const int h = blockIdx.x, tid = threadIdx.x;
  for (int idx = tid; idx < L_*D_; idx += 256){
    int l = idx >> 7, d = idx & 127;
    vupT[(size_t)h*D_*L_ + d*64 + l] = f2b(vup[(size_t)h*L_*D_ + idx]);
  }
}

// ---------------- fused qkv GEMM: qkvb[t][0..1151] ----------------
// C = A(hsb)[2048,2048] @ B(Wqkvb)[1152,2048]^T, bf16 out.
// cols 0..1023 scaled by isl*log2e (log2-domain q_latent); cols 1024.. raw.
__global__ __launch_bounds__(256)
void k_gemm_qkv(const ushort* __restrict__ A, const ushort* __restrict__ B,
                ushort* __restrict__ C){
  __shared__ ushort As[64*32];
  __shared__ ushort Bs[64*32];
  const int tid = threadIdx.x, lane = tid&63, wv = tid>>6;
  const int wm = wv & 1, wn = wv >> 1;
  const int l15 = lane&15, quad = lane>>4;
  const int m0 = blockIdx.y*64, n0 = blockIdx.x*64;
  const float scale = (n0 < 1024) ? 0.18033688f : 1.0f;  // isl*log2e
  floatx4 acc[2][2] = {};
  for (int k0=0; k0<E_; k0+=32){
    __syncthreads();
    { int c = wv*64 + lane; int row = c>>2, kc = (c&3)*8;
      glds16(A + (size_t)(m0+row)*E_ + k0 + kc, &As[c*8]);
      glds16(B + (size_t)(n0+row)*E_ + k0 + kc, &Bs[c*8]); }
    __syncthreads();
    bf16x8 af[2], bfr[2];
    #pragma unroll
    for (int mi=0;mi<2;++mi)
      af[mi] = *(const bf16x8*)(&As[(wm*32 + mi*16 + l15)*32 + quad*8]);
    #pragma unroll
    for (int ni=0;ni<2;++ni)
      bfr[ni] = *(const bf16x8*)(&Bs[(wn*32 + ni*16 + l15)*32 + quad*8]);
    #pragma unroll
    for (int mi=0;mi<2;++mi)
      #pragma unroll
      for (int ni=0;ni<2;++ni)
        acc[mi][ni] = __builtin_amdgcn_mfma_f32_16x16x32_bf16(af[mi], bfr[ni], acc[mi][ni], 0,0,0);
  }
  #pragma unroll
  for (int mi=0;mi<2;++mi){
    const int rb = m0 + wm*32 + mi*16 + quad*4;
    #pragma unroll
    for (int ni=0;ni<2;++ni){
      const int col = n0 + wn*32 + ni*16 + l15;
      #pragma unroll
      for (int r=0;r<4;++r)
        C[(size_t)(rb+r)*NQ + col] = f2b(acc[mi][ni][r]*scale);
    }
  }
}

// ---------------- m97-style GEMM (out-proj): C fp32 = A@B^T ----------------
template<int MT,int NT>
__global__ __launch_bounds__(256)
void gemm_glds(const ushort* __restrict__ A, const ushort* __restrict__ B,
               float* __restrict__ Cf, int M, int N, int K){
  constexpr int BM = 32*MT, BN = 32*NT;
  constexpr int IA = BM/64, IB = BN/64;
  __shared__ ushort As[BM*32];
  __shared__ ushort Bs[BN*32];
  const int tid = threadIdx.x, lane = tid&63, wv = tid>>6;
  const int wm = wv & 1, wn = wv >> 1;
  const int l15 = lane&15, quad = lane>>4;
  const int m0 = blockIdx.y*BM, n0 = blockIdx.x*BN;
  floatx4 acc[MT][NT] = {};
  for (int k0=0; k0<K; k0+=32){
    __syncthreads();
    #pragma unroll
    for (int j=0;j<IA;++j){
      int c = (j*4 + wv)*64 + lane; int row = c>>2, kc = (c&3)*8;
      glds16(A + (size_t)(m0+row)*K + k0 + kc, &As[c*8]);
    }
    #pragma unroll
    for (int j=0;j<IB;++j){
      int c = (j*4 + wv)*64 + lane; int row = c>>2, kc = (c&3)*8;
      glds16(B + (size_t)(n0+row)*K + k0 + kc, &Bs[c*8]);
    }
    __syncthreads();
    bf16x8 af[MT], bfr[NT];
    #pragma unroll
    for (int mi=0;mi<MT;++mi)
      af[mi] = *(const bf16x8*)(&As[(wm*MT*16 + mi*16 + l15)*32 + quad*8]);
    #pragma unroll
    for (int ni=0;ni<NT;++ni)
      bfr[ni] = *(const bf16x8*)(&Bs[(wn*NT*16 + ni*16 + l15)*32 + quad*8]);
    #pragma unroll
    for (int mi=0;mi<MT;++mi)
      #pragma unroll
      for (int ni=0;ni<NT;++ni)
        acc[mi][ni] = __builtin_amdgcn_mfma_f32_16x16x32_bf16(af[mi], bfr[ni], acc[mi][ni], 0,0,0);
  }
  #pragma unroll
  for (int mi=0;mi<MT;++mi){
    const int rb = m0 + wm*MT*16 + mi*16 + quad*4;
    #pragma unroll
    for (int ni=0;ni<NT;++ni){
      const int col = n0 + wn*NT*16 + ni*16 + l15;
      #pragma unroll
      for (int r=0;r<4;++r)
        Cf[(size_t)(rb+r)*N + col] = acc[mi][ni][r];
    }
  }
}

// ---------------- rowsum of 64 bf16 per output ----------------
// i -> t=i>>shift, g=i&((1<<shift)-1); sums src[t*stride + off + g*64 .. +63]
__global__ __launch_bounds__(256)
void k_rowsum_b(const ushort* __restrict__ src, float* __restrict__ dst,
                int n, int shift, int stride, int off){
  int i = blockIdx.x*256 + threadIdx.x;
  if (i >= n) return;
  int t = i >> shift, g = i & ((1<<shift)-1);
  const uint4* p = (const uint4*)(src + (size_t)t*stride + off + g*64);
  float s = 0.f;
  #pragma unroll
  for (int j=0;j<8;++j){
    uint4 u = p[j];
    const unsigned int uu[4] = {u.x,u.y,u.z,u.w};
    #pragma unroll
    for (int q=0;q<4;++q){
      s += __uint_as_float(uu[q] << 16);
      s += __uint_as_float(uu[q] & 0xffff0000u);
    }
  }
  dst[i] = s;
}

// ---------------- V_exp^T[h][d][t] via MFMA, register-only ----------------
__global__ __launch_bounds__(256)
void k_vexp_mfma(const ushort* __restrict__ qkvb, const ushort* __restrict__ vupT,
                 ushort* __restrict__ vexpT){
  const int h = blockIdx.y, t0 = blockIdx.x*64;
  const int tid = threadIdx.x, lane = tid&63, w = tid>>6;
  const int l15 = lane&15, quad = lane>>4;
  bf16x8 a[2][2], b[4][2];
  #pragma unroll
  for (int mt=0;mt<2;++mt)
    #pragma unroll
    for (int kk=0;kk<2;++kk)
      a[mt][kk] = *(const bf16x8*)(vupT + (size_t)h*D_*L_ + (w*32+mt*16+l15)*64 + kk*32 + quad*8);
  #pragma unroll
  for (int nt=0;nt<4;++nt)
    #pragma unroll
    for (int kk=0;kk<2;++kk)
      b[nt][kk] = *(const bf16x8*)(qkvb + (size_t)(t0+nt*16+l15)*NQ + 1088 + kk*32 + quad*8);
  floatx4 acc[2][4] = {};
  #pragma unroll
  for (int mt=0;mt<2;++mt)
    #pragma unroll
    for (int nt=0;nt<4;++nt)
      #pragma unroll
      for (int kk=0;kk<2;++kk)
        acc[mt][nt] = __builtin_amdgcn_mfma_f32_16x16x32_bf16(a[mt][kk], b[nt][kk], acc[mt][nt], 0,0,0);
  #pragma unroll
  for (int mt=0;mt<2;++mt)
    #pragma unroll
    for (int nt=0;nt<4;++nt)
      #pragma unroll
      for (int r=0;r<4;++r)
        vexpT[((size_t)h*D_ + w*32+mt*16+quad*4+r)*T_ + t0 + nt*16 + l15] = f2b(acc[mt][nt][r]);
}

// ---------------- flash attention, split-S ----------------
// Block = (head, 64-row Q-tile qt, S-chunk c of CH tiles). 4 waves.
// S^T layout (lane owns q=l15), log2-domain softmax, 2 barriers/tile,
// register-prefetch staging. Single-chunk -> ctx; else bf16 partial + (m,l).
__global__ __launch_bounds__(256, 3)
void k_attn(const ushort* __restrict__ qkvb,   // [T][1152] bf16
            const float*  __restrict__ rsq,    // [T][16]  (scaled rowsums)
            const float*  __restrict__ rsk,    // [T]
            const ushort* __restrict__ vexpT,  // [16][128][T] bf16
            ushort*       __restrict__ ctx,    // [T][2048] bf16
            ushort*       __restrict__ partO,  // [16][24][4][64][128] bf16
            float*        __restrict__ partML, // [16][24][4][64][2]
            int CH){
  constexpr int LP = 72;
  __shared__ ushort Ks[64*LP];
  __shared__ ushort Vts[128*LP];
  __shared__ ushort Ps[64*LP];
  __shared__ float  rsks[64];
  const int h  = blockIdx.y;
  const int bxr = (int)gridDim.x - 1 - (int)blockIdx.x;   // heavy tiles first
  int qt, c;
  if (CH == 8){
    if (bxr < 8){ qt = bxr; c = 0; }
    else if (bxr < 24){ int u = bxr-8;  qt = 8  + (u>>1); c = u&1; }
    else if (bxr < 48){ int u = bxr-24; qt = 16 + u/3;    c = u - (u/3)*3; }
    else               { int u = bxr-48; qt = 24 + (u>>2); c = u&3; }
  } else { qt = bxr; c = 0; }
  const int nct = (qt + CH) / CH;                 // ceil((qt+1)/CH)
  const int stBeg = c*CH, stEnd = min(qt, stBeg + CH - 1);
  const int t0 = qt*64;
  const int tid = threadIdx.x, lane = tid & 63, w = tid >> 6;
  const int l15 = lane & 15, quad = lane >> 4;

  const int qrow = t0 + w*16 + l15;
  const bf16x8 q0 = *(const bf16x8*)(qkvb + (size_t)qrow*NQ + h*64 + quad*8);
  const bf16x8 q1 = *(const bf16x8*)(qkvb + (size_t)qrow*NQ + h*64 + 32 + quad*8);
  const float rqv = rsq[(size_t)qrow*H_ + h] * 0.5f;      // already *isl*log2e

  float mrun = -INFINITY, lrun = 0.f;
  floatx4 o[8] = {};
  uint4 kreg[2], vreg[4]; float4 rr;

  // prologue: load tile stBeg into registers
  {
    const int sb = stBeg*64;
    #pragma unroll
    for (int j=0;j<2;++j){ int cc = tid + j*256;
      kreg[j] = *(const uint4*)(qkvb + (size_t)(sb + (cc>>3))*NQ + 1024 + (cc&7)*8); }
    #pragma unroll
    for (int j=0;j<4;++j){ int cc = tid + j*256;
      vreg[j] = *(const uint4*)(vexpT + ((size_t)h*128 + (cc>>3))*T_ + sb + (cc&7)*8); }
    if (tid < 16) rr = *(const float4*)(rsk + sb + tid*4);
  }

  for (int st=stBeg; st<=stEnd; ++st){
    __syncthreads();                                   // A: prev compute reads done
    #pragma unroll
    for (int j=0;j<2;++j){ int cc = tid + j*256;
      *(uint4*)(&Ks[(cc>>3)*LP + (cc&7)*8]) = kreg[j]; }
    #pragma unroll
    for (int j=0;j<4;++j){ int cc = tid + j*256;
      *(uint4*)(&Vts[(cc>>3)*LP + (cc&7)*8]) = vreg[j]; }
    if (tid < 16) *(float4*)(&rsks[tid*4]) = rr;
    __syncthreads();                                   // B: stores visible
    if (st < stEnd){                                   // prefetch next tile
      const int s1 = (st+1)*64;
      #pragma unroll
      for (int j=0;j<2;++j){ int cc = tid + j*256;
        kreg[j] = *(const uint4*)(qkvb + (size_t)(s1 + (cc>>3))*NQ + 1024 + (cc&7)*8); }
      #pragma unroll
      for (int j=0;j<4;++j){ int cc = tid + j*256;
        vreg[j] = *(const uint4*)(vexpT + ((size_t)h*128 + (cc>>3))*T_ + s1 + (cc&7)*8); }
      if (tid < 16) rr = *(const float4*)(rsk + s1 + tid*4);
    }
    const int s0 = st*64;
    // ---- S^T = K Q^T : lane owns q=l15, s=jt*16+quad*4+r ----
    floatx4 sT[4] = {};
    #pragma unroll
    for (int jt=0;jt<4;++jt){
      bf16x8 k0f = *(const bf16x8*)(&Ks[(jt*16+l15)*LP + quad*8]);
      sT[jt] = __builtin_amdgcn_mfma_f32_16x16x32_bf16(k0f, q0, sT[jt], 0,0,0);
      bf16x8 k1f = *(const bf16x8*)(&Ks[(jt*16+l15)*LP + 32 + quad*8]);
      sT[jt] = __builtin_amdgcn_mfma_f32_16x16x32_bf16(k1f, q1, sT[jt], 0,0,0);
    }
    // ---- mask + rank-1 band (diagonal tiles only) + online softmax ----
    float xs[16];
    float mloc = -3.0e38f;
    if (st >= qt-1){                                   // edge: band and/or mask
      #pragma unroll
      for (int jt=0;jt<4;++jt){
        const float4 rk4 = *(const float4*)(&rsks[jt*16 + quad*4]);
        #pragma unroll
        for (int r=0;r<4;++r){
          const int sg = s0 + jt*16 + quad*4 + r;
          const int dd = qrow - sg;
          float x = sT[jt][r];
          x = (dd <= 64) ? x + rqv*((const float*)&rk4)[r] : x;
          x = (dd < 0)   ? -3.0e38f : x;
          xs[jt*4+r] = x; mloc = fmaxf(mloc, x);
        }
      }
    } else {                                           // interior: no band, no mask
      #pragma unroll
      for (int jt=0;jt<4;++jt)
        #pragma unroll
        for (int r=0;r<4;++r){
          float x = sT[jt][r];
          xs[jt*4+r] = x; mloc = fmaxf(mloc, x);
        }
    }
    mloc = fmaxf(mloc, __shfl_xor(mloc, 16));
    mloc = fmaxf(mloc, __shfl_xor(mloc, 32));
    const float mn = fmaxf(mrun, mloc);
    const float al = exp2f(mrun - mn);
    float pr[16];
    float ss = 0.f;
    #pragma unroll
    for (int i=0;i<16;++i){ float p = exp2f(xs[i]-mn); pr[i]=p; ss+=p; }
    ss += __shfl_xor(ss, 16); ss += __shfl_xor(ss, 32);
    lrun = lrun*al + ss; mrun = mn;
    // ---- P write (wave-private region, same-wave ordering) ----
    #pragma unroll
    for (int jt=0;jt<4;++jt){
      ushort4 pw; pw.x=f2b(pr[jt*4]); pw.y=f2b(pr[jt*4+1]);
      pw.z=f2b(pr[jt*4+2]); pw.w=f2b(pr[jt*4+3]);
      *(ushort4*)(&Ps[(w*16+l15)*LP + jt*16 + quad*4]) = pw;
    }
    // ---- rescale O rows ----
    float alr[4];
    #pragma unroll
    for (int r=0;r<4;++r) alr[r] = __shfl(al, quad*4 + r);
    #pragma unroll
    for (int nt=0;nt<8;++nt){
      o[nt][0]*=alr[0]; o[nt][1]*=alr[1]; o[nt][2]*=alr[2]; o[nt][3]*=alr[3];
    }
    // ---- O += P V ----
    #pragma unroll
    for (int kks=0;kks<2;++kks){
      bf16x8 pf = *(const bf16x8*)(&Ps[(w*16+l15)*LP + kks*32 + quad*8]);
      #pragma unroll
      for (int nt=0;nt<8;++nt){
        bf16x8 vf = *(const bf16x8*)(&Vts[(nt*16+l15)*LP + kks*32 + quad*8]);
        o[nt] = __builtin_amdgcn_mfma_f32_16x16x32_bf16(pf, vf, o[nt], 0,0,0);
      }
    }
  }
  // ---- epilogue ----
  const float linv = 1.f/lrun;
  float lr4[4];
  #pragma unroll
  for (int r=0;r<4;++r) lr4[r] = __shfl(linv, quad*4 + r);
  if (nct == 1){
    #pragma unroll
    for (int r=0;r<4;++r){
      const int row = t0 + w*16 + quad*4 + r;
      #pragma unroll
      for (int nt=0;nt<8;++nt)
        ctx[(size_t)row*E_ + h*D_ + nt*16 + l15] = f2b(o[nt][r]*lr4[r]);
    }
  } else {
    const int slot = (h*24 + (qt-8))*4 + c;
    ushort* po = partO + (size_t)slot*64*128;
    #pragma unroll
    for (int r=0;r<4;++r){
      const int row = w*16 + quad*4 + r;
      #pragma unroll
      for (int nt=0;nt<8;++nt)
        po[(size_t)row*128 + nt*16 + l15] = f2b(o[nt][r]*lr4[r]);
    }
    if (quad == 0){
      float2 ml; ml.x = mrun; ml.y = lrun;
      ((float2*)partML)[(size_t)slot*64 + w*16 + l15] = ml;
    }
  }
}

// ---------------- merge partials -> ctx (qt >= 8) ----------------
__global__ __launch_bounds__(256)
void k_merge(const ushort* __restrict__ partO, const float* __restrict__ partML,
             ushort* __restrict__ ctx){
  const int h = blockIdx.y, qt = 8 + blockIdx.x;
  const int nct = (qt + 8) / 8;
  const int tid = threadIdx.x;
  const int r = tid >> 2, d0 = (tid & 3)*32;
  const int sbase = (h*24 + (qt-8))*4;
  float m[4], l[4], M = -INFINITY;
  for (int c=0;c<4;++c){
    if (c < nct){
      float2 v = ((const float2*)partML)[(size_t)(sbase+c)*64 + r];
      m[c]=v.x; l[c]=v.y; M = fmaxf(M, v.x);
    }
  }
  float lt = 0.f, wgt[4];
  for (int c=0;c<4;++c){
    if (c < nct){ wgt[c] = exp2f(m[c]-M)*l[c]; lt += wgt[c]; }
  }
  const float inv = 1.f/lt;
  float acc[32];
  #pragma unroll
  for (int i=0;i<32;++i) acc[i]=0.f;
  for (int c=0;c<4;++c){
    if (c >= nct) break;
    const float sc = wgt[c]*inv;
    const ushort* po = partO + (size_t)(sbase+c)*64*128 + r*128 + d0;
    #pragma unroll
    for (int k=0;k<4;++k){
      uint4 u = ((const uint4*)po)[k];
      const unsigned int uu[4] = {u.x,u.y,u.z,u.w};
      #pragma unroll
      for (int q=0;q<4;++q){
        acc[k*8+q*2]   += sc*__uint_as_float(uu[q] << 16);
        acc[k*8+q*2+1] += sc*__uint_as_float(uu[q] & 0xffff0000u);
      }
    }
  }
  ushort* dst = ctx + (size_t)(qt*64 + r)*E_ + h*D_ + d0;
  #pragma unroll
  for (int k=0;k<4;++k){
    ushort4 ov; ov.x=f2b(acc[k*8]); ov.y=f2b(acc[k*8+1]);
    ov.z=f2b(acc[k*8+2]); ov.w=f2b(acc[k*8+3]);
    ushort4 ov2; ov2.x=f2b(acc[k*8+4]); ov2.y=f2b(acc[k*8+5]);
    ov2.z=f2b(acc[k*8+6]); ov2.w=f2b(acc[k*8+7]);
    *(ushort4*)(dst + k*8)     = ov;
    *(ushort4*)(dst + k*8 + 4) = ov2;
  }
}

// ---------------- launch ----------------
extern "C" void kernel_launch(void* const* d_in, const int* in_sizes, int n_in,
                              void* d_out, int out_size, void* d_ws, size_t ws_size,
                              hipStream_t stream) {
  const float* hs  = (const float*)d_in[0];
  const float* Wq  = (const float*)d_in[1];
  const float* Wk  = (const float*)d_in[2];
  const float* Wv  = (const float*)d_in[3];
  const float* q2l = (const float*)d_in[4];
  const float* vup = (const float*)d_in[5];
  const float* Wo  = (const float*)d_in[6];
  float* out = (float*)d_out;
  char* ws = (char*)d_ws;

  // workspace layout (bytes)
  ushort* hsb   = (ushort*)(ws + 0);           // [2048][2048] bf16
  ushort* Wqkvb = (ushort*)(ws + 8388608);     // [1152][2048] bf16 (ql|k|v)
  ushort* Wob   = (ushort*)(ws + 13107200);    // [2048][2048] bf16
  ushort* qkvb  = (ushort*)(ws + 21495808);    // [2048][1152] bf16
  ushort* vupT  = (ushort*)(ws + 26214400);    // [16][128][64] bf16
  float*  rsqp  = (float*) (ws + 26476544);    // [2048][16]
  float*  rskp  = (float*) (ws + 26607616);    // [2048]
  ushort* vexpT = (ushort*)(ws + 26615808);    // [16][128][2048] bf16
  ushort* ctxb  = (ushort*)(ws + 35004416);    // [2048][2048] bf16
  ushort* partO = (ushort*)(ws + 43393024);    // [16][24][4][64][128] bf16
  float*  partML= (float*) (ws + 68558848);    // [16][24][4][64][2]
  const size_t NEED = 69345280;
  const int CH = (ws_size >= NEED) ? 8 : 32;   // split-S unless ws too small

  // 1) bf16 conversions
  k_f2b<<<4096, 256, 0, stream>>>(hs, hsb, T_*E_);
  k_f2b<<<128,  256, 0, stream>>>(Wk, Wqkvb + (size_t)1024*E_, L_*E_);
  k_f2b<<<128,  256, 0, stream>>>(Wv, Wqkvb + (size_t)1088*E_, L_*E_);
  k_f2b<<<4096, 256, 0, stream>>>(Wo, Wob, E_*E_);

  // 2) weight prep
  k_prep_wql<<<dim3(16,2,16), 128, 0, stream>>>(Wq, q2l, Wqkvb);
  k_prep_vupT<<<16, 256, 0, stream>>>(vup, vupT);

  // 3) fused q_latent|k|v GEMM -> qkvb [2048][1152]
  k_gemm_qkv<<<dim3(18,32), 256, 0, stream>>>(hsb, Wqkvb, qkvb);

  // 4) rowsums (rsq from scaled ql cols; rsk from raw k cols)
  k_rowsum_b<<<128, 256, 0, stream>>>(qkvb, rsqp, T_*H_, 4, NQ, 0);
  k_rowsum_b<<<8,   256, 0, stream>>>(qkvb, rskp, T_,    0, NQ, 1024);

  // 5) V_exp^T via MFMA
  k_vexp_mfma<<<dim3(32,16), 256, 0, stream>>>(qkvb, vupT, vexpT);

  // 6) flash attention (split-S) -> ctx / partials
  k_attn<<<dim3(CH==8 ? 80 : 32, 16), 256, 0, stream>>>(
      qkvb, rsqp, rskp, vexpT, ctxb, partO, partML, CH);

  // 7) merge partials (only when split)
  if (CH == 8)
    k_merge<<<dim3(24,16), 256, 0, stream>>>(partO, partML, ctxb);

  // 8) out = ctx @ Wo^T  (fp32 to d_out)
  gemm_glds<4,2><<<dim3(32,16), 256, 0, stream>>>(ctxb, Wob, out, T_, E_, E_);
}